// Round 1
// baseline (51508.136 us; speedup 1.0000x reference)
//
#include <hip/hip_runtime.h>
#include <math.h>

#define DICT 1024
#define IN_DIM 512
#define BATCH 256
#define LMBD_F 0.1f
#define TOL2 1e-8f       // tol^2 (compare squared norms)
#define MAX_ITERS 1000
#define LM 64            // Lanczos iterations

// ---- workspace layout (float offsets) ----
#define OFF_G      0u            // 1024*1024 = 1048576
#define OFF_B      1048576u      // 256*1024  = 262144
#define OFF_HA     1310720u      // 256*1024  = 262144
#define OFF_V      1572864u      // 1024
#define OFF_VPREV  1573888u      // 1024
#define OFF_W      1574912u      // 1024
#define OFF_ALPHA  1575936u      // 64
#define OFF_BETA   1576000u      // 64
#define OFF_SCAL   1576064u      // [0]=lr [1]=thresh
#define OFF_RD     1576080u      // rowdelta 3*256
#define WS_FLOATS  (OFF_RD + 768u)

// ---------------- init ----------------
__global__ void k_init(float* ws) {
    int t = threadIdx.x;  // 1024 threads
    ws[OFF_V + t] = 0.03125f;       // ones/sqrt(1024): unit norm start
    ws[OFF_VPREV + t] = 0.f;
    if (t < 768) ws[OFF_RD + t] = 0.f;
    if (t < LM) { ws[OFF_ALPHA + t] = 0.f; ws[OFF_BETA + t] = 0.f; }
}

// ---------------- generic NT GEMM: C[M,N] = A[M,K] * B[N,K]^T ----------------
// tiles 32x32, k-chunk 32, 256 threads. One-time setup kernel (G, b).
__global__ void k_gemm_nt(float* __restrict__ C, const float* __restrict__ A,
                          const float* __restrict__ B, int M, int N, int K) {
    __shared__ float As[32][33];
    __shared__ float Bs[32][33];
    const int tid = threadIdx.x;
    const int m0 = blockIdx.y * 32, n0 = blockIdx.x * 32;
    const int lrw = tid >> 3;          // 0..31 row of tile
    const int lc4 = (tid & 7) * 4;     // k offset (float4)
    const int ty = tid >> 4, tx = tid & 15;
    float acc00 = 0, acc01 = 0, acc10 = 0, acc11 = 0;
    for (int k0 = 0; k0 < K; k0 += 32) {
        float4 av = *(const float4*)&A[(m0 + lrw) * K + k0 + lc4];
        float4 bv = *(const float4*)&B[(n0 + lrw) * K + k0 + lc4];
        __syncthreads();
        As[lrw][lc4 + 0] = av.x; As[lrw][lc4 + 1] = av.y;
        As[lrw][lc4 + 2] = av.z; As[lrw][lc4 + 3] = av.w;
        Bs[lrw][lc4 + 0] = bv.x; Bs[lrw][lc4 + 1] = bv.y;
        Bs[lrw][lc4 + 2] = bv.z; Bs[lrw][lc4 + 3] = bv.w;
        __syncthreads();
#pragma unroll
        for (int k = 0; k < 32; ++k) {
            float a0 = As[ty * 2][k], a1 = As[ty * 2 + 1][k];
            float b0 = Bs[tx * 2][k], b1 = Bs[tx * 2 + 1][k];
            acc00 += a0 * b0; acc01 += a0 * b1;
            acc10 += a1 * b0; acc11 += a1 * b1;
        }
    }
    C[(m0 + ty * 2) * N + n0 + tx * 2] = acc00;
    C[(m0 + ty * 2) * N + n0 + tx * 2 + 1] = acc01;
    C[(m0 + ty * 2 + 1) * N + n0 + tx * 2] = acc10;
    C[(m0 + ty * 2 + 1) * N + n0 + tx * 2 + 1] = acc11;
}

// ---------------- Lanczos: w = G * v ----------------
__global__ void k_lanczos_av(float* ws) {
    const float* G = ws + OFF_G;
    const float* v = ws + OFF_V;
    int row = blockIdx.x * 4 + (threadIdx.x >> 6);
    int lane = threadIdx.x & 63;
    const float* gr = G + row * DICT;
    float s = 0.f;
    for (int k = lane; k < DICT; k += 64) s += gr[k] * v[k];
    for (int off = 32; off; off >>= 1) s += __shfl_down(s, off);
    if (lane == 0) ws[OFF_W + row] = s;
}

// ---------------- Lanczos: alpha/beta update, 1 WG of 1024 ----------------
__global__ void k_lanczos_fin(float* ws, int j) {
    __shared__ float red[16];
    __shared__ float sc[2];
    int t = threadIdx.x;
    float wt = ws[OFF_W + t], vt = ws[OFF_V + t], vpt = ws[OFF_VPREV + t];
    float p = vt * wt;
    for (int off = 32; off; off >>= 1) p += __shfl_down(p, off);
    if ((t & 63) == 0) red[t >> 6] = p;
    __syncthreads();
    if (t == 0) { float a = 0; for (int i = 0; i < 16; ++i) a += red[i]; sc[0] = a; }
    __syncthreads();
    float alpha = sc[0];
    float bprev = (j > 0) ? ws[OFF_BETA + j - 1] : 0.f;
    wt = wt - alpha * vt - bprev * vpt;
    p = wt * wt;
    __syncthreads();
    for (int off = 32; off; off >>= 1) p += __shfl_down(p, off);
    if ((t & 63) == 0) red[t >> 6] = p;
    __syncthreads();
    if (t == 0) { float a = 0; for (int i = 0; i < 16; ++i) a += red[i]; sc[1] = sqrtf(a); }
    __syncthreads();
    float beta = sc[1];
    float vn = (beta > 1e-20f) ? wt / beta : 0.f;
    ws[OFF_VPREV + t] = vt;
    ws[OFF_V + t] = vn;
    if (t == 0) {
        ws[OFF_ALPHA + j] = alpha;
        ws[OFF_BETA + j] = (beta > 1e-20f) ? beta : 0.f;
    }
}

// ---------------- tridiag lambda_max (Sturm bisection) -> lr, thresh ----------------
__global__ void k_eig_lr(float* ws) {
    if (threadIdx.x != 0) return;
    double a[LM], b[LM];
    for (int i = 0; i < LM; ++i) { a[i] = ws[OFF_ALPHA + i]; b[i] = ws[OFF_BETA + i]; }
    double hi = 0.0, lo = 0.0;
    for (int i = 0; i < LM; ++i) {
        double r = a[i] + fabs(b[i]) + (i ? fabs(b[i - 1]) : 0.0);
        if (r > hi) hi = r;
    }
    for (int it = 0; it < 100; ++it) {
        double mid = 0.5 * (lo + hi);
        int cnt = 0;
        double d = 1.0;
        for (int i = 0; i < LM; ++i) {
            double off2 = i ? b[i - 1] * b[i - 1] : 0.0;
            d = (a[i] - mid) - off2 / d;
            if (d == 0.0) d = -1e-300;
            if (d < 0.0) cnt++;
        }
        if (cnt >= LM) hi = mid; else lo = mid;
    }
    float lam = (float)(0.5 * (lo + hi));
    float lr = 0.99f / lam;
    ws[OFF_SCAL] = lr;
    ws[OFF_SCAL + 1] = lr * LMBD_F;
}

// ---------------- one ISTA iteration ----------------
// h_new = soft(h + lr*(b - h*G), thresh); rowdelta 3-slot rotation for stop.
// even iter: in=d_out, out=hA ; odd iter: in=hA, out=d_out. iter999 (odd) -> d_out fresh.
__device__ __forceinline__ float softthr(float aa, float th) {
    float s = fabsf(aa) - th;
    return s > 0.f ? copysignf(s, aa) : 0.f;
}

__launch_bounds__(256)
__global__ void k_ista(float* __restrict__ ws, float* __restrict__ dout, int iter) {
    const int tid = threadIdx.x;
    float* rd = ws + OFF_RD;
    const int slot_read = (iter + 2) % 3;
    const int slot_acc  = iter % 3;
    const int slot_zero = (iter + 1) % 3;

    __shared__ float smax[4];
    bool stop = false;
    if (iter > 0) {
        float m = rd[slot_read * 256 + tid];
        for (int off = 32; off; off >>= 1) m = fmaxf(m, __shfl_xor(m, off));
        if ((tid & 63) == 0) smax[tid >> 6] = m;
        __syncthreads();
        float mm = fmaxf(fmaxf(smax[0], smax[1]), fmaxf(smax[2], smax[3]));
        stop = (mm < TOL2);
    }
    rd[slot_zero * 256 + tid] = 0.f;   // prepare slot for next kernel (always)
    if (stop) return;                  // converged: all later kernels no-op too

    const float* G = ws + OFF_G;
    const float* bv_ = ws + OFF_B;
    float* hA = ws + OFF_HA;
    const float* h_in = (iter & 1) ? hA : dout;
    float* h_out      = (iter & 1) ? dout : hA;
    const float lr = ws[OFF_SCAL], th = ws[OFF_SCAL + 1];

    const int by = blockIdx.y;      // 0..15 row tile (16 rows)
    const int bx = blockIdx.x;      // 0..15 col tile (64 cols)
    const int ty = tid >> 4;        // row in tile
    const int tx = tid & 15;        // col quad
    const int row = by * 16 + ty;
    const int col = bx * 64 + tx * 4;

    __shared__ float As[16][64];
    float ax = 0.f, ay = 0.f, az = 0.f, aw = 0.f;

    for (int k0 = 0; k0 < DICT; k0 += 64) {
        __syncthreads();
        *(float4*)&As[tid >> 4][(tid & 15) * 4] =
            *(const float4*)&h_in[(by * 16 + (tid >> 4)) * DICT + k0 + (tid & 15) * 4];
        __syncthreads();
#pragma unroll 4
        for (int kk = 0; kk < 64; kk += 4) {
            float4 a4 = *(const float4*)&As[ty][kk];
            float4 g0 = *(const float4*)&G[(k0 + kk + 0) * DICT + col];
            float4 g1 = *(const float4*)&G[(k0 + kk + 1) * DICT + col];
            float4 g2 = *(const float4*)&G[(k0 + kk + 2) * DICT + col];
            float4 g3 = *(const float4*)&G[(k0 + kk + 3) * DICT + col];
            ax += a4.x * g0.x + a4.y * g1.x + a4.z * g2.x + a4.w * g3.x;
            ay += a4.x * g0.y + a4.y * g1.y + a4.z * g2.y + a4.w * g3.y;
            az += a4.x * g0.z + a4.y * g1.z + a4.z * g2.z + a4.w * g3.z;
            aw += a4.x * g0.w + a4.y * g1.w + a4.z * g2.w + a4.w * g3.w;
        }
    }

    const int gi = row * DICT + col;
    float4 bb = *(const float4*)&bv_[gi];
    float4 hh = *(const float4*)&h_in[gi];
    float4 hn;
    hn.x = softthr(hh.x + lr * (bb.x - ax), th);
    hn.y = softthr(hh.y + lr * (bb.y - ay), th);
    hn.z = softthr(hh.z + lr * (bb.z - az), th);
    hn.w = softthr(hh.w + lr * (bb.w - aw), th);
    *(float4*)&h_out[gi] = hn;

    float dx = hn.x - hh.x, dy = hn.y - hh.y, dz = hn.z - hh.z, dw = hn.w - hh.w;
    float ssq = dx * dx + dy * dy + dz * dz + dw * dw;
    // reduce across the 16 lanes of this row (lanes are 16-aligned groups)
    for (int off = 1; off < 16; off <<= 1) ssq += __shfl_xor(ssq, off);
    if (tx == 0) atomicAdd(&rd[slot_acc * 256 + row], ssq);
}

extern "C" void kernel_launch(void* const* d_in, const int* in_sizes, int n_in,
                              void* d_out, int out_size, void* d_ws, size_t ws_size,
                              hipStream_t stream) {
    const float* x = (const float*)d_in[0];   // [256,512]
    const float* D = (const float*)d_in[1];   // [1024,512]
    float* out = (float*)d_out;               // [256,1024] = h
    float* ws = (float*)d_ws;

    // h0 = 0 lives in d_out (input of iteration 0)
    hipMemsetAsync(d_out, 0, (size_t)BATCH * DICT * sizeof(float), stream);
    k_init<<<dim3(1), dim3(1024), 0, stream>>>(ws);

    // G = D D^T  (NT gemm, M=N=1024, K=512)
    k_gemm_nt<<<dim3(32, 32), dim3(256), 0, stream>>>(ws + OFF_G, D, D, 1024, 1024, 512);
    // b = x D^T  (M=256, N=1024, K=512)
    k_gemm_nt<<<dim3(32, 8), dim3(256), 0, stream>>>(ws + OFF_B, x, D, 256, 1024, 512);

    // Lanczos for lambda_max(G)
    for (int j = 0; j < LM; ++j) {
        k_lanczos_av<<<dim3(256), dim3(256), 0, stream>>>(ws);
        k_lanczos_fin<<<dim3(1), dim3(1024), 0, stream>>>(ws, j);
    }
    k_eig_lr<<<dim3(1), dim3(64), 0, stream>>>(ws);

    // ISTA iterations (graph nodes; converged iterations early-out)
    for (int i = 0; i < MAX_ITERS; ++i) {
        k_ista<<<dim3(16, 16), dim3(256), 0, stream>>>(ws, out, i);
    }
}

// Round 2
// 19965.950 us; speedup vs baseline: 2.5798x; 2.5798x over previous
//
#include <hip/hip_runtime.h>
#include <math.h>

#define DICT 1024
#define IN_DIM 512
#define BATCH 256
#define LMBD_F 0.1f
#define TOL2 1e-8f       // tol^2 (compare squared row norms)
#define MAX_ITERS 1000
#define LM 64            // Lanczos iterations

// ---- workspace layout (float offsets) ----
#define OFF_G      0u            // 1024*1024
#define OFF_B      1048576u      // 256*1024
#define OFF_HA     1310720u      // 256*1024
#define OFF_V      1572864u      // 1024
#define OFF_VPREV  1573888u      // 1024
#define OFF_W      1574912u      // 1024
#define OFF_ALPHA  1575936u      // 64
#define OFF_BETA   1576000u      // 64
#define OFF_SCAL   1576064u      // [0]=lr [1]=thresh
#define OFF_RD     1576080u      // rowdelta 3*256
#define OFF_CP     1576848u      // copied flags, 256
#define WS_FLOATS  (OFF_CP + 256u)

// ---------------- init (runs every launch: resets all iteration state) ----------------
__global__ void k_init(float* ws) {
    int t = threadIdx.x;  // 1024 threads
    ws[OFF_V + t] = 0.03125f;       // ones/sqrt(1024)
    ws[OFF_VPREV + t] = 0.f;
    if (t < 768) ws[OFF_RD + t] = 0.f;
    if (t < 256) ws[OFF_CP + t] = 0.f;
    if (t < LM) { ws[OFF_ALPHA + t] = 0.f; ws[OFF_BETA + t] = 0.f; }
}

// ---------------- one-time NT GEMM: C[M,N] = A[M,K] * B[N,K]^T ----------------
__global__ void k_gemm_nt(float* __restrict__ C, const float* __restrict__ A,
                          const float* __restrict__ B, int M, int N, int K) {
    __shared__ float As[32][33];
    __shared__ float Bs[32][33];
    const int tid = threadIdx.x;
    const int m0 = blockIdx.y * 32, n0 = blockIdx.x * 32;
    const int lrw = tid >> 3;
    const int lc4 = (tid & 7) * 4;
    const int ty = tid >> 4, tx = tid & 15;
    float acc00 = 0, acc01 = 0, acc10 = 0, acc11 = 0;
    for (int k0 = 0; k0 < K; k0 += 32) {
        float4 av = *(const float4*)&A[(m0 + lrw) * K + k0 + lc4];
        float4 bv = *(const float4*)&B[(n0 + lrw) * K + k0 + lc4];
        __syncthreads();
        As[lrw][lc4 + 0] = av.x; As[lrw][lc4 + 1] = av.y;
        As[lrw][lc4 + 2] = av.z; As[lrw][lc4 + 3] = av.w;
        Bs[lrw][lc4 + 0] = bv.x; Bs[lrw][lc4 + 1] = bv.y;
        Bs[lrw][lc4 + 2] = bv.z; Bs[lrw][lc4 + 3] = bv.w;
        __syncthreads();
#pragma unroll
        for (int k = 0; k < 32; ++k) {
            float a0 = As[ty * 2][k], a1 = As[ty * 2 + 1][k];
            float b0 = Bs[tx * 2][k], b1 = Bs[tx * 2 + 1][k];
            acc00 += a0 * b0; acc01 += a0 * b1;
            acc10 += a1 * b0; acc11 += a1 * b1;
        }
    }
    C[(m0 + ty * 2) * N + n0 + tx * 2] = acc00;
    C[(m0 + ty * 2) * N + n0 + tx * 2 + 1] = acc01;
    C[(m0 + ty * 2 + 1) * N + n0 + tx * 2] = acc10;
    C[(m0 + ty * 2 + 1) * N + n0 + tx * 2 + 1] = acc11;
}

// ---------------- Lanczos: w = G * v ----------------
__global__ void k_lanczos_av(float* ws) {
    const float* G = ws + OFF_G;
    const float* v = ws + OFF_V;
    int row = blockIdx.x * 4 + (threadIdx.x >> 6);
    int lane = threadIdx.x & 63;
    const float* gr = G + row * DICT;
    float s = 0.f;
    for (int k = lane; k < DICT; k += 64) s += gr[k] * v[k];
    for (int off = 32; off; off >>= 1) s += __shfl_down(s, off);
    if (lane == 0) ws[OFF_W + row] = s;
}

// ---------------- Lanczos: alpha/beta update ----------------
__global__ void k_lanczos_fin(float* ws, int j) {
    __shared__ float red[16];
    __shared__ float sc[2];
    int t = threadIdx.x;
    float wt = ws[OFF_W + t], vt = ws[OFF_V + t], vpt = ws[OFF_VPREV + t];
    float p = vt * wt;
    for (int off = 32; off; off >>= 1) p += __shfl_down(p, off);
    if ((t & 63) == 0) red[t >> 6] = p;
    __syncthreads();
    if (t == 0) { float a = 0; for (int i = 0; i < 16; ++i) a += red[i]; sc[0] = a; }
    __syncthreads();
    float alpha = sc[0];
    float bprev = (j > 0) ? ws[OFF_BETA + j - 1] : 0.f;
    wt = wt - alpha * vt - bprev * vpt;
    p = wt * wt;
    __syncthreads();
    for (int off = 32; off; off >>= 1) p += __shfl_down(p, off);
    if ((t & 63) == 0) red[t >> 6] = p;
    __syncthreads();
    if (t == 0) { float a = 0; for (int i = 0; i < 16; ++i) a += red[i]; sc[1] = sqrtf(a); }
    __syncthreads();
    float beta = sc[1];
    float vn = (beta > 1e-20f) ? wt / beta : 0.f;
    ws[OFF_VPREV + t] = vt;
    ws[OFF_V + t] = vn;
    if (t == 0) {
        ws[OFF_ALPHA + j] = alpha;
        ws[OFF_BETA + j] = (beta > 1e-20f) ? beta : 0.f;
    }
}

// ---------------- tridiag lambda_max (Sturm bisection) -> lr, thresh ----------------
__global__ void k_eig_lr(float* ws) {
    if (threadIdx.x != 0) return;
    double a[LM], b[LM];
    for (int i = 0; i < LM; ++i) { a[i] = ws[OFF_ALPHA + i]; b[i] = ws[OFF_BETA + i]; }
    double hi = 0.0, lo = 0.0;
    for (int i = 0; i < LM; ++i) {
        double r = a[i] + fabs(b[i]) + (i ? fabs(b[i - 1]) : 0.0);
        if (r > hi) hi = r;
    }
    for (int it = 0; it < 100; ++it) {
        double mid = 0.5 * (lo + hi);
        int cnt = 0;
        double d = 1.0;
        for (int i = 0; i < LM; ++i) {
            double off2 = i ? b[i - 1] * b[i - 1] : 0.0;
            d = (a[i] - mid) - off2 / d;
            if (d == 0.0) d = -1e-300;
            if (d < 0.0) cnt++;
        }
        if (cnt >= LM) hi = mid; else lo = mid;
    }
    float lam = (float)(0.5 * (lo + hi));
    float lr = 0.99f / lam;
    ws[OFF_SCAL] = lr;
    ws[OFF_SCAL + 1] = lr * LMBD_F;
}

// ---------------- one ISTA iteration: LDS-staged split-K GEMM ----------------
// h_new = soft(h + lr*(b - h*G), thresh)
// grid (16,16): tile = 16 rows x 64 cols; 512 threads = 8 waves, split-K.
__device__ __forceinline__ float softthr(float aa, float th) {
    float s = fabsf(aa) - th;
    return s > 0.f ? copysignf(s, aa) : 0.f;
}

__launch_bounds__(512)
__global__ void k_ista(float* __restrict__ ws, float* __restrict__ dout, int iter) {
    const int tid = threadIdx.x;
    float* rd = ws + OFF_RD;
    float* copied = ws + OFF_CP;
    const int slot_read = (iter + 2) % 3;
    const int slot_acc  = iter % 3;
    const int slot_zero = (iter + 1) % 3;

    const int bx = blockIdx.x;      // col tile 0..15 (64 cols)
    const int by = blockIdx.y;      // row tile 0..15 (16 rows)
    const int R0 = by * 16, C0 = bx * 64;
    const int fid = by * 16 + bx;

    __shared__ float smax[4];
    const int w = tid >> 6, lane = tid & 63;

    // ---- convergence prologue ----
    bool stop = false;
    if (iter > 0) {
        if (w < 4) {
            float m = rd[slot_read * 256 + tid];
            for (int off = 32; off; off >>= 1) m = fmaxf(m, __shfl_xor(m, off));
            if (lane == 0) smax[w] = m;
        }
        __syncthreads();
        float mm = fmaxf(fmaxf(smax[0], smax[1]), fmaxf(smax[2], smax[3]));
        stop = (mm < TOL2);
    }
    if (tid < 256) rd[slot_zero * 256 + tid] = 0.f;  // keep slot rotation alive

    float* hA = ws + OFF_HA;
    const float* h_in = (iter & 1) ? hA : dout;
    float* h_out      = (iter & 1) ? dout : hA;

    if (stop) {
        // Final h was produced by iteration iter-1. If that wrote hA (iter-1 even),
        // copy this block's tile to dout exactly once.
        if (copied[fid] == 0.f) {
            if (tid == 0) copied[fid] = 1.f;
            if (iter >= 1 && ((iter - 1) & 1) == 0) {
                int r = tid >> 5, c = (tid & 31) * 2;
                int gi = (R0 + r) * DICT + C0 + c;
                *(float2*)&dout[gi] = *(const float2*)&hA[gi];
            }
        }
        return;
    }

    const float* G = ws + OFF_G;
    const float* bv_ = ws + OFF_B;
    const float lr = ws[OFF_SCAL], th = ws[OFF_SCAL + 1];

    __shared__ float At[128][18];    // transposed h tile chunk  (9.2 KB)
    __shared__ float Gs[128][64];    // G chunk                  (32 KB)
    __shared__ float Ps[8][16][64];  // per-wave partials        (32 KB)

    const int rg = lane >> 3;        // 0..7 : row pair group
    const int cg = lane & 7;         // 0..7 : col octet group

    float acc[2][8];
#pragma unroll
    for (int j = 0; j < 2; ++j)
#pragma unroll
        for (int i = 0; i < 8; ++i) acc[j][i] = 0.f;

    const int ka = tid & 127, rr = tid >> 7;   // A staging map
    for (int kc = 0; kc < 8; ++kc) {
        const int k0 = kc * 128;
        __syncthreads();
        // stage A (transposed): 16 rows x 128 k
#pragma unroll
        for (int j = 0; j < 4; ++j)
            At[ka][rr * 4 + j] = h_in[(R0 + rr * 4 + j) * DICT + k0 + ka];
        // stage G: 128 k x 64 cols
#pragma unroll
        for (int j = 0; j < 4; ++j) {
            int q = tid + j * 512;
            int kg = q >> 4, c4 = q & 15;
            *(float4*)&Gs[kg][c4 * 4] = *(const float4*)&G[(k0 + kg) * DICT + C0 + c4 * 4];
        }
        __syncthreads();
        // compute: wave w handles k = w*16 .. w*16+15 of this chunk
#pragma unroll
        for (int kk = 0; kk < 16; ++kk) {
            const int k = w * 16 + kk;
            float2 a = *(const float2*)&At[k][rg * 2];
            float4 g0 = *(const float4*)&Gs[k][cg * 8];
            float4 g1 = *(const float4*)&Gs[k][cg * 8 + 4];
            acc[0][0] += a.x * g0.x; acc[0][1] += a.x * g0.y;
            acc[0][2] += a.x * g0.z; acc[0][3] += a.x * g0.w;
            acc[0][4] += a.x * g1.x; acc[0][5] += a.x * g1.y;
            acc[0][6] += a.x * g1.z; acc[0][7] += a.x * g1.w;
            acc[1][0] += a.y * g0.x; acc[1][1] += a.y * g0.y;
            acc[1][2] += a.y * g0.z; acc[1][3] += a.y * g0.w;
            acc[1][4] += a.y * g1.x; acc[1][5] += a.y * g1.y;
            acc[1][6] += a.y * g1.z; acc[1][7] += a.y * g1.w;
        }
    }

    // ---- cross-wave reduction of split-K partials ----
    __syncthreads();
#pragma unroll
    for (int j = 0; j < 2; ++j) {
        *(float4*)&Ps[w][rg * 2 + j][cg * 8]     = make_float4(acc[j][0], acc[j][1], acc[j][2], acc[j][3]);
        *(float4*)&Ps[w][rg * 2 + j][cg * 8 + 4] = make_float4(acc[j][4], acc[j][5], acc[j][6], acc[j][7]);
    }
    __syncthreads();

    // ---- epilogue: 2 outputs per thread ----
    const int r = tid >> 5;           // 0..15
    const int c = (tid & 31) * 2;     // 0..62
    float s0 = 0.f, s1 = 0.f;
#pragma unroll
    for (int ww = 0; ww < 8; ++ww) {
        float2 p = *(const float2*)&Ps[ww][r][c];
        s0 += p.x; s1 += p.y;
    }
    const int gi = (R0 + r) * DICT + C0 + c;
    float2 bb = *(const float2*)&bv_[gi];
    float2 hh = *(const float2*)&h_in[gi];
    float n0 = softthr(hh.x + lr * (bb.x - s0), th);
    float n1 = softthr(hh.y + lr * (bb.y - s1), th);
    float2 hn; hn.x = n0; hn.y = n1;
    *(float2*)&h_out[gi] = hn;

    float d0 = n0 - hh.x, d1 = n1 - hh.y;
    float ssq = d0 * d0 + d1 * d1;
#pragma unroll
    for (int off = 1; off < 32; off <<= 1) ssq += __shfl_xor(ssq, off);
    if ((tid & 31) == 0) atomicAdd(&rd[slot_acc * 256 + R0 + r], ssq);
}

extern "C" void kernel_launch(void* const* d_in, const int* in_sizes, int n_in,
                              void* d_out, int out_size, void* d_ws, size_t ws_size,
                              hipStream_t stream) {
    const float* x = (const float*)d_in[0];   // [256,512]
    const float* D = (const float*)d_in[1];   // [1024,512]
    float* out = (float*)d_out;               // [256,1024] = h
    float* ws = (float*)d_ws;

    hipMemsetAsync(d_out, 0, (size_t)BATCH * DICT * sizeof(float), stream);
    k_init<<<dim3(1), dim3(1024), 0, stream>>>(ws);

    // G = D D^T ; b = x D^T
    k_gemm_nt<<<dim3(32, 32), dim3(256), 0, stream>>>(ws + OFF_G, D, D, 1024, 1024, 512);
    k_gemm_nt<<<dim3(32, 8), dim3(256), 0, stream>>>(ws + OFF_B, x, D, 256, 1024, 512);

    // Lanczos for lambda_max(G)
    for (int j = 0; j < LM; ++j) {
        k_lanczos_av<<<dim3(256), dim3(256), 0, stream>>>(ws);
        k_lanczos_fin<<<dim3(1), dim3(1024), 0, stream>>>(ws, j);
    }
    k_eig_lr<<<dim3(1), dim3(64), 0, stream>>>(ws);

    // ISTA iterations
    for (int i = 0; i < MAX_ITERS; ++i) {
        k_ista<<<dim3(16, 16), dim3(512), 0, stream>>>(ws, out, i);
    }
}

// Round 3
// 14812.303 us; speedup vs baseline: 3.4774x; 1.3479x over previous
//
#include <hip/hip_runtime.h>
#include <math.h>

#define DICT 1024
#define IN_DIM 512
#define BATCH 256
#define LMBD_F 0.1f
#define TOL2 1e-8f       // tol^2 (compare squared row norms)
#define MAX_ITERS 1000
#define LM 64            // Lanczos iterations

// ---- workspace layout (float offsets) ----
#define OFF_G      0u            // 1024*1024 f32 Gram
#define OFF_B      1048576u      // 256*1024 f32  b = x D^T
#define OFF_HA     1310720u      // 256*1024 f32  h ping (pong = d_out)
#define OFF_V      1572864u      // 1024
#define OFF_VPREV  1573888u      // 1024
#define OFF_W      1574912u      // 1024
#define OFF_ALPHA  1575936u      // 64
#define OFF_BETA   1576000u      // 64
#define OFF_SCAL   1576064u      // [0]=lr [1]=thresh
#define OFF_RD     1576080u      // rowdelta 3*256
#define OFF_CP     1576848u      // copied flags, 256
#define OFF_BF     1577216u      // bf16 h arrays: 4 x 262144 ushort (hiA,loA,hiB,loB)
#define OFF_GBF    2101504u      // bf16 G arrays: 2 x 1048576 ushort (Ghi,Glo)
// total ~3.15M floats = 12.6 MB

typedef __attribute__((ext_vector_type(8))) short short8v;  // 8 bf16 (4 VGPRs)
typedef __attribute__((ext_vector_type(4))) float f32x4;    // MFMA C/D

#define MFMA16(a, b, c) __builtin_amdgcn_mfma_f32_16x16x32_bf16(a, b, c, 0, 0, 0)

__device__ __forceinline__ ushort f2bf(float v) {      // f32 -> bf16 (RNE)
    union { float f; unsigned u; } x; x.f = v;
    unsigned r = x.u + 0x7fffu + ((x.u >> 16) & 1u);
    return (ushort)(r >> 16);
}
__device__ __forceinline__ float bf2f(ushort b) {
    union { unsigned u; float f; } x; x.u = ((unsigned)b) << 16;
    return x.f;
}
__device__ __forceinline__ float softthr(float aa, float th) {
    float s = fabsf(aa) - th;
    return s > 0.f ? copysignf(s, aa) : 0.f;
}

// ---------------- init (runs every launch: resets all iteration state) ----------------
__global__ void k_init(float* ws) {
    int t = threadIdx.x;  // 1024 threads
    ws[OFF_V + t] = 0.03125f;       // ones/sqrt(1024)
    ws[OFF_VPREV + t] = 0.f;
    if (t < 768) ws[OFF_RD + t] = 0.f;
    if (t < 256) ws[OFF_CP + t] = 0.f;
    if (t < LM) { ws[OFF_ALPHA + t] = 0.f; ws[OFF_BETA + t] = 0.f; }
}

// ---------------- one-time NT GEMM: C[M,N] = A[M,K] * B[N,K]^T ----------------
__global__ void k_gemm_nt(float* __restrict__ C, const float* __restrict__ A,
                          const float* __restrict__ B, int M, int N, int K) {
    __shared__ float As[32][33];
    __shared__ float Bs[32][33];
    const int tid = threadIdx.x;
    const int m0 = blockIdx.y * 32, n0 = blockIdx.x * 32;
    const int lrw = tid >> 3;
    const int lc4 = (tid & 7) * 4;
    const int ty = tid >> 4, tx = tid & 15;
    float acc00 = 0, acc01 = 0, acc10 = 0, acc11 = 0;
    for (int k0 = 0; k0 < K; k0 += 32) {
        float4 av = *(const float4*)&A[(m0 + lrw) * K + k0 + lc4];
        float4 bv = *(const float4*)&B[(n0 + lrw) * K + k0 + lc4];
        __syncthreads();
        As[lrw][lc4 + 0] = av.x; As[lrw][lc4 + 1] = av.y;
        As[lrw][lc4 + 2] = av.z; As[lrw][lc4 + 3] = av.w;
        Bs[lrw][lc4 + 0] = bv.x; Bs[lrw][lc4 + 1] = bv.y;
        Bs[lrw][lc4 + 2] = bv.z; Bs[lrw][lc4 + 3] = bv.w;
        __syncthreads();
#pragma unroll
        for (int k = 0; k < 32; ++k) {
            float a0 = As[ty * 2][k], a1 = As[ty * 2 + 1][k];
            float b0 = Bs[tx * 2][k], b1 = Bs[tx * 2 + 1][k];
            acc00 += a0 * b0; acc01 += a0 * b1;
            acc10 += a1 * b0; acc11 += a1 * b1;
        }
    }
    C[(m0 + ty * 2) * N + n0 + tx * 2] = acc00;
    C[(m0 + ty * 2) * N + n0 + tx * 2 + 1] = acc01;
    C[(m0 + ty * 2 + 1) * N + n0 + tx * 2] = acc10;
    C[(m0 + ty * 2 + 1) * N + n0 + tx * 2 + 1] = acc11;
}

// ---------------- convert G f32 -> (Ghi, Glo) bf16, once ----------------
__global__ void k_conv_g(float* ws) {
    const int i = (blockIdx.x * 256 + threadIdx.x) * 4;
    const float* G = ws + OFF_G;
    ushort* Ghi = (ushort*)(ws + OFF_GBF);
    ushort* Glo = Ghi + 1048576u;
    float4 g = *(const float4*)&G[i];
    ushort h0 = f2bf(g.x), h1 = f2bf(g.y), h2 = f2bf(g.z), h3 = f2bf(g.w);
    *(ushort4*)&Ghi[i] = make_ushort4(h0, h1, h2, h3);
    ushort l0 = f2bf(g.x - bf2f(h0)), l1 = f2bf(g.y - bf2f(h1));
    ushort l2 = f2bf(g.z - bf2f(h2)), l3 = f2bf(g.w - bf2f(h3));
    *(ushort4*)&Glo[i] = make_ushort4(l0, l1, l2, l3);
}

// ---------------- Lanczos: w = G * v ----------------
__global__ void k_lanczos_av(float* ws) {
    const float* G = ws + OFF_G;
    const float* v = ws + OFF_V;
    int row = blockIdx.x * 4 + (threadIdx.x >> 6);
    int lane = threadIdx.x & 63;
    const float* gr = G + row * DICT;
    float s = 0.f;
    for (int k = lane; k < DICT; k += 64) s += gr[k] * v[k];
    for (int off = 32; off; off >>= 1) s += __shfl_down(s, off);
    if (lane == 0) ws[OFF_W + row] = s;
}

// ---------------- Lanczos: alpha/beta update ----------------
__global__ void k_lanczos_fin(float* ws, int j) {
    __shared__ float red[16];
    __shared__ float sc[2];
    int t = threadIdx.x;
    float wt = ws[OFF_W + t], vt = ws[OFF_V + t], vpt = ws[OFF_VPREV + t];
    float p = vt * wt;
    for (int off = 32; off; off >>= 1) p += __shfl_down(p, off);
    if ((t & 63) == 0) red[t >> 6] = p;
    __syncthreads();
    if (t == 0) { float a = 0; for (int i = 0; i < 16; ++i) a += red[i]; sc[0] = a; }
    __syncthreads();
    float alpha = sc[0];
    float bprev = (j > 0) ? ws[OFF_BETA + j - 1] : 0.f;
    wt = wt - alpha * vt - bprev * vpt;
    p = wt * wt;
    __syncthreads();
    for (int off = 32; off; off >>= 1) p += __shfl_down(p, off);
    if ((t & 63) == 0) red[t >> 6] = p;
    __syncthreads();
    if (t == 0) { float a = 0; for (int i = 0; i < 16; ++i) a += red[i]; sc[1] = sqrtf(a); }
    __syncthreads();
    float beta = sc[1];
    float vn = (beta > 1e-20f) ? wt / beta : 0.f;
    ws[OFF_VPREV + t] = vt;
    ws[OFF_V + t] = vn;
    if (t == 0) {
        ws[OFF_ALPHA + j] = alpha;
        ws[OFF_BETA + j] = (beta > 1e-20f) ? beta : 0.f;
    }
}

// ---------------- tridiag lambda_max (Sturm bisection) -> lr, thresh ----------------
__global__ void k_eig_lr(float* ws) {
    if (threadIdx.x != 0) return;
    double a[LM], b[LM];
    for (int i = 0; i < LM; ++i) { a[i] = ws[OFF_ALPHA + i]; b[i] = ws[OFF_BETA + i]; }
    double hi = 0.0, lo = 0.0;
    for (int i = 0; i < LM; ++i) {
        double r = a[i] + fabs(b[i]) + (i ? fabs(b[i - 1]) : 0.0);
        if (r > hi) hi = r;
    }
    for (int it = 0; it < 100; ++it) {
        double mid = 0.5 * (lo + hi);
        int cnt = 0;
        double d = 1.0;
        for (int i = 0; i < LM; ++i) {
            double off2 = i ? b[i - 1] * b[i - 1] : 0.0;
            d = (a[i] - mid) - off2 / d;
            if (d == 0.0) d = -1e-300;
            if (d < 0.0) cnt++;
        }
        if (cnt >= LM) hi = mid; else lo = mid;
    }
    float lam = (float)(0.5 * (lo + hi));
    float lr = 0.99f / lam;
    ws[OFF_SCAL] = lr;
    ws[OFF_SCAL + 1] = lr * LMBD_F;
}

// ---------------- one ISTA iteration: split-bf16 MFMA GEMM, LDS-free ----------------
// S = h*G via (hi+lo)x(hi+lo) 3-product MFMA; h_new = soft(h + lr*(b - S), th).
// grid (32,8): tile 32 rows x 32 cols; 256 threads = 4 waves, split-K (256 each).
// B fragments read G rows (G symmetric). A/B use identical k-addressing ->
// dot products exact under any internal k-permutation.
__launch_bounds__(256)
__global__ void k_ista(float* __restrict__ ws, float* __restrict__ dout, int iter) {
    const int tid = threadIdx.x;
    const int w = tid >> 6, lane = tid & 63;
    float* rd = ws + OFF_RD;
    float* copied = ws + OFF_CP;
    const int slot_read = (iter + 2) % 3;
    const int slot_acc  = iter % 3;
    const int slot_zero = (iter + 1) % 3;

    const int bx = blockIdx.x;      // 0..31 col tile
    const int by = blockIdx.y;      // 0..7  row tile
    const int R0 = by * 32, C0 = bx * 32;
    const int fid = by * 32 + bx;

    __shared__ float smax[4];
    __shared__ float Ps[4][32][36];  // [wave][col][row], padded

    // ---- convergence prologue ----
    bool stop = false;
    if (iter > 0) {
        float m = rd[slot_read * 256 + tid];
#pragma unroll
        for (int off = 32; off; off >>= 1) m = fmaxf(m, __shfl_xor(m, off));
        if (lane == 0) smax[w] = m;
        __syncthreads();
        float mm = fmaxf(fmaxf(smax[0], smax[1]), fmaxf(smax[2], smax[3]));
        stop = (mm < TOL2);
    }
    rd[slot_zero * 256 + tid] = 0.f;   // keep slot rotation alive

    float* hA = ws + OFF_HA;
    const float* h_in = (iter & 1) ? hA : dout;
    float* h_out      = (iter & 1) ? dout : hA;

    if (stop) {
        if (copied[fid] == 0.f) {
            if (tid == 0) copied[fid] = 1.f;
            if (iter >= 1 && ((iter - 1) & 1) == 0) {
                int r = tid >> 3, c = (tid & 7) * 4;
                int gi = (R0 + r) * DICT + C0 + c;
                *(float4*)&dout[gi] = *(const float4*)&hA[gi];
            }
        }
        return;
    }

    // ---- bf16 operand pointers (ping-pong on h) ----
    ushort* bfb = (ushort*)(ws + OFF_BF);
    const ushort* hi_in = bfb + ((iter & 1) ? 524288u : 0u);
    const ushort* lo_in = hi_in + 262144u;
    ushort* hi_out = bfb + ((iter & 1) ? 0u : 524288u);
    ushort* lo_out = hi_out + 262144u;
    const ushort* Ghi = (const ushort*)(ws + OFF_GBF);
    const ushort* Glo = Ghi + 1048576u;

    const float lr = ws[OFF_SCAL], th = ws[OFF_SCAL + 1];
    const float* bv_ = ws + OFF_B;

    // ---- MFMA GEMM: wave w covers k in [w*256, w*256+256) ----
    const int kb = w * 256 + ((lane >> 4) << 3);
    const int rA0 = (R0 + (lane & 15)) * DICT + kb;
    const int rA1 = rA0 + 16 * DICT;
    const int rB0 = (C0 + (lane & 15)) * DICT + kb;
    const int rB1 = rB0 + 16 * DICT;

    f32x4 acc[3][2][2];
#pragma unroll
    for (int p = 0; p < 3; ++p)
#pragma unroll
        for (int i = 0; i < 2; ++i)
#pragma unroll
            for (int j = 0; j < 2; ++j)
                acc[p][i][j] = (f32x4){0.f, 0.f, 0.f, 0.f};

#pragma unroll
    for (int ks = 0; ks < 8; ++ks) {
        const int o = ks * 32;
        short8v a0h = *(const short8v*)&hi_in[rA0 + o];
        short8v a1h = *(const short8v*)&hi_in[rA1 + o];
        short8v a0l = *(const short8v*)&lo_in[rA0 + o];
        short8v a1l = *(const short8v*)&lo_in[rA1 + o];
        short8v b0h = *(const short8v*)&Ghi[rB0 + o];
        short8v b1h = *(const short8v*)&Ghi[rB1 + o];
        short8v b0l = *(const short8v*)&Glo[rB0 + o];
        short8v b1l = *(const short8v*)&Glo[rB1 + o];
        acc[0][0][0] = MFMA16(a0h, b0h, acc[0][0][0]);
        acc[0][0][1] = MFMA16(a0h, b1h, acc[0][0][1]);
        acc[0][1][0] = MFMA16(a1h, b0h, acc[0][1][0]);
        acc[0][1][1] = MFMA16(a1h, b1h, acc[0][1][1]);
        acc[1][0][0] = MFMA16(a0h, b0l, acc[1][0][0]);
        acc[1][0][1] = MFMA16(a0h, b1l, acc[1][0][1]);
        acc[1][1][0] = MFMA16(a1h, b0l, acc[1][1][0]);
        acc[1][1][1] = MFMA16(a1h, b1l, acc[1][1][1]);
        acc[2][0][0] = MFMA16(a0l, b0h, acc[2][0][0]);
        acc[2][0][1] = MFMA16(a0l, b1h, acc[2][0][1]);
        acc[2][1][0] = MFMA16(a1l, b0h, acc[2][1][0]);
        acc[2][1][1] = MFMA16(a1l, b1h, acc[2][1][1]);
    }

    // ---- write per-wave partials to LDS (transposed: [col][row]) ----
#pragma unroll
    for (int i = 0; i < 2; ++i)
#pragma unroll
        for (int j = 0; j < 2; ++j) {
            f32x4 s = acc[0][i][j] + acc[1][i][j] + acc[2][i][j];
            int col = 16 * j + (lane & 15);
            int row = 16 * i + ((lane >> 4) << 2);
            *(f32x4*)&Ps[w][col][row] = s;
        }
    __syncthreads();

    // ---- cross-wave reduce + epilogue: 1 row x 4 cols per thread ----
    const int er = tid >> 3;          // 0..31
    const int ec = (tid & 7) * 4;     // 0,4,..,28
    float s0 = 0.f, s1 = 0.f, s2 = 0.f, s3 = 0.f;
#pragma unroll
    for (int ww = 0; ww < 4; ++ww) {
        s0 += Ps[ww][ec + 0][er];
        s1 += Ps[ww][ec + 1][er];
        s2 += Ps[ww][ec + 2][er];
        s3 += Ps[ww][ec + 3][er];
    }
    const int gi = (R0 + er) * DICT + C0 + ec;
    float4 bb = *(const float4*)&bv_[gi];
    float4 hh = *(const float4*)&h_in[gi];
    float n0 = softthr(hh.x + lr * (bb.x - s0), th);
    float n1 = softthr(hh.y + lr * (bb.y - s1), th);
    float n2 = softthr(hh.z + lr * (bb.z - s2), th);
    float n3 = softthr(hh.w + lr * (bb.w - s3), th);
    *(float4*)&h_out[gi] = make_float4(n0, n1, n2, n3);

    ushort q0 = f2bf(n0), q1 = f2bf(n1), q2 = f2bf(n2), q3 = f2bf(n3);
    *(ushort4*)&hi_out[gi] = make_ushort4(q0, q1, q2, q3);
    ushort z0 = f2bf(n0 - bf2f(q0)), z1 = f2bf(n1 - bf2f(q1));
    ushort z2 = f2bf(n2 - bf2f(q2)), z3 = f2bf(n3 - bf2f(q3));
    *(ushort4*)&lo_out[gi] = make_ushort4(z0, z1, z2, z3);

    float d0 = n0 - hh.x, d1 = n1 - hh.y, d2 = n2 - hh.z, d3 = n3 - hh.w;
    float ssq = d0 * d0 + d1 * d1 + d2 * d2 + d3 * d3;
#pragma unroll
    for (int off = 1; off < 8; off <<= 1) ssq += __shfl_xor(ssq, off);
    if ((tid & 7) == 0) atomicAdd(&rd[slot_acc * 256 + R0 + er], ssq);
}

extern "C" void kernel_launch(void* const* d_in, const int* in_sizes, int n_in,
                              void* d_out, int out_size, void* d_ws, size_t ws_size,
                              hipStream_t stream) {
    const float* x = (const float*)d_in[0];   // [256,512]
    const float* D = (const float*)d_in[1];   // [1024,512]
    float* out = (float*)d_out;               // [256,1024] = h
    float* ws = (float*)d_ws;

    // h0 = 0 (f32 ping in d_out) and bf16 A-set (hiA, loA) = 0
    hipMemsetAsync(d_out, 0, (size_t)BATCH * DICT * sizeof(float), stream);
    hipMemsetAsync((char*)(ws + OFF_BF), 0, 1048576, stream);
    k_init<<<dim3(1), dim3(1024), 0, stream>>>(ws);

    // G = D D^T ; bf16 split of G ; b = x D^T
    k_gemm_nt<<<dim3(32, 32), dim3(256), 0, stream>>>(ws + OFF_G, D, D, 1024, 1024, 512);
    k_conv_g<<<dim3(1024), dim3(256), 0, stream>>>(ws);
    k_gemm_nt<<<dim3(32, 8), dim3(256), 0, stream>>>(ws + OFF_B, x, D, 256, 1024, 512);

    // Lanczos for lambda_max(G)
    for (int j = 0; j < LM; ++j) {
        k_lanczos_av<<<dim3(256), dim3(256), 0, stream>>>(ws);
        k_lanczos_fin<<<dim3(1), dim3(1024), 0, stream>>>(ws, j);
    }
    k_eig_lr<<<dim3(1), dim3(64), 0, stream>>>(ws);

    // ISTA iterations
    for (int i = 0; i < MAX_ITERS; ++i) {
        k_ista<<<dim3(32, 8), dim3(256), 0, stream>>>(ws, out, i);
    }
}